// Round 2
// baseline (519.033 us; speedup 1.0000x reference)
//
#include <hip/hip_runtime.h>
#include <hip/hip_bf16.h>

#define N_TOK 4096
#define DIM   1024
#define VOCAB 32000
#define BM 128
#define BN 128
#define BK 64           // 64-deep K stage: 32 MFMAs per barrier drain, 16 iters
#define SMOOTH 0.1f
#define CVT_B 4096      // grid-stride blocks for the f32->bf16 stream
#define TGT_B 1024      // 4 tokens per block

typedef __attribute__((ext_vector_type(8))) short short8v;
typedef __attribute__((ext_vector_type(4))) float float4v;

__device__ __forceinline__ unsigned short f2bf(float f) {
  union { float f; unsigned u; } c; c.f = f;
  unsigned r = c.u + 0x7fffu + ((c.u >> 16) & 1u);
  return (unsigned short)(r >> 16);
}

__device__ __forceinline__ void gload_lds16(const unsigned short* g, unsigned short* l) {
  __builtin_amdgcn_global_load_lds((const __attribute__((address_space(1))) unsigned int*)g,
                                   (__attribute__((address_space(3))) unsigned int*)l,
                                   16, 0, 0);
}

// ---------------------------------------------------------------------------
// Fused prep: ONE dispatch replaces {memset, cvt_bf16_2, tgt_dot}.
//   blocks [0, CVT_B):              grid-strided f32->bf16 for x and W
//   blocks [CVT_B, CVT_B+TGT_B):    exact-f32 target logits (1 wave / token)
//   blocks [CVT_B+TGT_B, +8):       zero rowExp/rowSum (32 KB)
// ---------------------------------------------------------------------------
__global__ __launch_bounds__(256)
void prep(const float* __restrict__ x, const float* __restrict__ W, const int* __restrict__ y,
          unsigned short* __restrict__ Xb, unsigned short* __restrict__ Wb,
          float* __restrict__ rowBufs, float* __restrict__ tgtRow) {
  const int b = blockIdx.x;
  const int tid = threadIdx.x;

  if (b < CVT_B) {
    const int n4x = N_TOK * DIM / 4, n4w = VOCAB * DIM / 4;
    const int total = n4x + n4w;
    for (int i = b * 256 + tid; i < total; i += CVT_B * 256) {
      const float4* s; unsigned long long* d; int j;
      if (i < n4x) { s = (const float4*)x; d = (unsigned long long*)Xb; j = i; }
      else         { s = (const float4*)W; d = (unsigned long long*)Wb; j = i - n4x; }
      float4 v = s[j];
      d[j] = (unsigned long long)f2bf(v.x)
           | ((unsigned long long)f2bf(v.y) << 16)
           | ((unsigned long long)f2bf(v.z) << 32)
           | ((unsigned long long)f2bf(v.w) << 48);
    }
  } else if (b < CVT_B + TGT_B) {
    const int n = (b - CVT_B) * 4 + (tid >> 6);
    const int lane = tid & 63;
    const float4* xr = (const float4*)(x + (size_t)n * DIM);
    const float4* wr = (const float4*)(W + (size_t)y[n] * DIM);
    float d = 0.f;
#pragma unroll
    for (int i = 0; i < 4; ++i) {
      float4 a = xr[lane + 64 * i], w = wr[lane + 64 * i];
      d += a.x * w.x + a.y * w.y + a.z * w.z + a.w * w.w;
    }
#pragma unroll
    for (int off = 32; off > 0; off >>= 1) d += __shfl_xor(d, off, 64);
    if (lane == 0) tgtRow[n] = d;
  } else {
    // zero rowExp+rowSum: 8 blocks x 256 threads x 16 B = 32 KB
    float4* p = (float4*)rowBufs;
    p[(b - CVT_B - TGT_B) * 256 + tid] = (float4){0.f, 0.f, 0.f, 0.f};
  }
}

// C = Xb[4096,1024] * Wb[32000,1024]^T with fused per-row sum(exp) / sum.
// 128x128 tile, 4 waves 2x2, BK=64. XOR-swizzled LDS: LDS[row][cb] holds
// global colblock cb ^ (row&7)  (cb = 8-bf16 = 16B block) -> ds_read_b128
// spreads all 8 colblocks across the 32 banks. Proven 932 TF / 0 conflicts.
__global__ __launch_bounds__(256, 3)
void gemm_ce(const unsigned short* __restrict__ Xb, const unsigned short* __restrict__ Wb,
             float* __restrict__ rowExp, float* __restrict__ rowSum) {
  __shared__ __align__(16) unsigned short As[BM * BK];  // 16 KB, [128][64]
  __shared__ __align__(16) unsigned short Bs[BN * BK];  // 16 KB

  const int ib = blockIdx.x;   // token tile (32)
  const int jb = blockIdx.y;   // vocab tile (250)
  const int row0 = ib * BM;
  const int col0 = jb * BN;

  const int tid  = threadIdx.x;
  const int wv   = tid >> 6;
  const int lane = tid & 63;
  const int wr = wv >> 1, wc = wv & 1;
  const int quad = lane >> 4;
  const int r16  = lane & 15;
  // staging map: 1 KB per inst = 8 rows x 8 colblocks; LDS slot fixed at
  // base+lane*16, but lane FETCHES global colblock (lane&7)^(lrow&7).
  const int lrow = lane >> 3;
  const int gcb  = (lane & 7) ^ (lrow & 7);   // swizzled source colblock
  const int r8   = r16 & 7;                   // reader's row&7

  float4v acc[4][4];
#pragma unroll
  for (int i = 0; i < 4; ++i)
#pragma unroll
    for (int j = 0; j < 4; ++j) acc[i][j] = (float4v){0.f, 0.f, 0.f, 0.f};

  for (int kk = 0; kk < DIM; kk += BK) {
    __syncthreads();   // prior ds_reads done before overwrite
#pragma unroll
    for (int c = 0; c < 4; ++c) {
      const int rA = wv * 32 + c * 8;   // wave-uniform 8-row slab base
      gload_lds16(Xb + (size_t)(row0 + rA + lrow) * DIM + kk + gcb * 8, &As[rA * BK]);
      gload_lds16(Wb + (size_t)(col0 + rA + lrow) * DIM + kk + gcb * 8, &Bs[rA * BK]);
    }
    __syncthreads();   // staging visible (vmcnt drain)

#pragma unroll
    for (int ks = 0; ks < 2; ++ks) {
      const int cbA = (ks * 4 + quad) ^ r8;   // swizzled LDS colblock
      short8v af[4], bf[4];
#pragma unroll
      for (int i = 0; i < 4; ++i)
        af[i] = *(const short8v*)&As[(wr * 64 + i * 16 + r16) * BK + cbA * 8];
#pragma unroll
      for (int j = 0; j < 4; ++j)
        bf[j] = *(const short8v*)&Bs[(wc * 64 + j * 16 + r16) * BK + cbA * 8];
#pragma unroll
      for (int i = 0; i < 4; ++i)
#pragma unroll
        for (int j = 0; j < 4; ++j)
          acc[i][j] = __builtin_amdgcn_mfma_f32_16x16x32_bf16(af[i], bf[j], acc[i][j], 0, 0, 0);
    }
  }

  // Fused epilogue: per-row sum(exp(logit)), sum(logit).
  // C/D layout: col = r16, row = quad*4 + reg (within each 16x16 tile).
  // LDS pre-reduction (proven in R1: WRITE_SIZE 64->4 MB): the two wc-waves
  // sharing each row combine in LDS, then ONE global atomic per row/array.
  __syncthreads();
  float* red = (float*)As;   // 256 floats: [0..127]=exp, [128..255]=raw
  red[tid] = 0.f;
  __syncthreads();
#pragma unroll
  for (int i = 0; i < 4; ++i)
#pragma unroll
    for (int r = 0; r < 4; ++r) {
      float se = 0.f, ss = 0.f;
#pragma unroll
      for (int j = 0; j < 4; ++j) {
        const float v = acc[i][j][r];
        ss += v;
        se += __expf(v);
      }
#pragma unroll
      for (int off = 1; off < 16; off <<= 1) {
        se += __shfl_xor(se, off, 64);
        ss += __shfl_xor(ss, off, 64);
      }
      if (r16 == 0) {
        const int rloc = wr * 64 + i * 16 + quad * 4 + r;
        atomicAdd(&red[rloc], se);
        atomicAdd(&red[128 + rloc], ss);
      }
    }
  __syncthreads();
  if (tid < 128)       atomicAdd(&rowExp[row0 + tid], red[tid]);
  else if (tid < 256)  atomicAdd(&rowSum[row0 + (tid - 128)], red[tid]);
}

// loss = (1/N) sum lse - (1-s)/N * sum tgt - s/(N*V) * sum(all logits)
__global__ __launch_bounds__(1024)
void finalize_kernel(const float* __restrict__ rowExp, const float* __restrict__ rowSum,
                     const float* __restrict__ tgtRow, float* __restrict__ out) {
  __shared__ float s1[1024], s2[1024], s3[1024];
  const int t = threadIdx.x;
  float a = 0.f, b = 0.f, c = 0.f;
  for (int n = t; n < N_TOK; n += 1024) {
    a += logf(rowExp[n]);
    b += rowSum[n];
    c += tgtRow[n];
  }
  s1[t] = a; s2[t] = b; s3[t] = c;
  __syncthreads();
  for (int o = 512; o > 0; o >>= 1) {
    if (t < o) { s1[t] += s1[t + o]; s2[t] += s2[t + o]; s3[t] += s3[t + o]; }
    __syncthreads();
  }
  if (t == 0) {
    const float inviN = 1.0f / (float)N_TOK;
    out[0] = s1[0] * inviN
           - (1.0f - SMOOTH) * s3[0] * inviN
           - SMOOTH * s2[0] / ((float)N_TOK * (float)VOCAB);
  }
}

extern "C" void kernel_launch(void* const* d_in, const int* in_sizes, int n_in,
                              void* d_out, int out_size, void* d_ws, size_t ws_size,
                              hipStream_t stream) {
  const float* x = (const float*)d_in[0];
  const float* W = (const float*)d_in[1];
  const int*   y = (const int*)d_in[2];
  float* out = (float*)d_out;

  char* ws = (char*)d_ws;
  float* rowExp = (float*)(ws);              // 4096 f32
  float* rowSum = (float*)(ws + 16384);      // 4096 f32 (contiguous with rowExp)
  float* tgtRow = (float*)(ws + 32768);      // 4096 f32 (fully written, no memset)
  unsigned short* Xb = (unsigned short*)(ws + 65536);                            // 8.4 MB
  unsigned short* Wb = (unsigned short*)(ws + 65536 + (size_t)N_TOK * DIM * 2);  // 65.5 MB

  // One prep dispatch: cvt (grid-stride) + tgt_dot + rowbuf zeroing.
  prep<<<CVT_B + TGT_B + 8, 256, 0, stream>>>(x, W, y, Xb, Wb, rowExp, tgtRow);

  dim3 grid(N_TOK / BM, VOCAB / BN);  // (32, 250): token-fastest for XCD locality
  gemm_ce<<<grid, 256, 0, stream>>>(Xb, Wb, rowExp, rowSum);

  finalize_kernel<<<1, 1024, 0, stream>>>(rowExp, rowSum, tgtRow, out);
}